// Round 8
// baseline (294.544 us; speedup 1.0000x reference)
//
#include <hip/hip_runtime.h>

#define D 64
#define SCAN_CHUNK 1024
#define NXCD 8
#define BUCKET_BLOCKS 512

typedef unsigned short ushort_t;
typedef __bf16 bf16_t;
typedef __bf16 bf16x8 __attribute__((ext_vector_type(8)));
typedef float f32x4 __attribute__((ext_vector_type(4)));

__device__ __forceinline__ ushort_t f2bf(float v) {
    unsigned u = __float_as_uint(v);
    return (ushort_t)((u + 0x7FFF + ((u >> 16) & 1)) >> 16);
}
__device__ __forceinline__ float bf2f(ushort_t h) {
    return __uint_as_float((unsigned)h << 16);
}

// ---------------------------------------------------------------------------
// d_ws layout (tier 0):
//   off[int,N+1] | cur[int,N] | ssrc[int,E] | blockSums[int,256] |
//   gcnt[int,128] | buf[uint2, 8*cap] | xh[ushort,N*64] | hb[ushort,N*64] |
//   w1t[ushort,4096] | w2t[ushort,4096]
// ---------------------------------------------------------------------------

__global__ __launch_bounds__(256) void zero_kernel(int* __restrict__ p, int n) {
    int gid = blockIdx.x * 256 + threadIdx.x;
    if (gid < n) p[gid] = 0;
}

// x (fp32) -> xh (bf16 RNE)
__global__ __launch_bounds__(256) void cast_kernel(const float4* __restrict__ x,
                                                   ushort4* __restrict__ xh,
                                                   int n4) {
    int gid = blockIdx.x * 256 + threadIdx.x;
    if (gid >= n4) return;
    float4 v = x[gid];
    ushort4 o;
    o.x = f2bf(v.x); o.y = f2bf(v.y); o.z = f2bf(v.z); o.w = f2bf(v.w);
    xh[gid] = o;
}

// W[k*64+n] (fp32) -> wT[n*64+k] (bf16)
__global__ __launch_bounds__(256) void cast_wT_kernel(const float* __restrict__ W1,
                                                      const float* __restrict__ W2,
                                                      ushort_t* __restrict__ w1t,
                                                      ushort_t* __restrict__ w2t) {
    const float* W = (blockIdx.x == 0) ? W1 : W2;
    ushort_t* T = (blockIdx.x == 0) ? w1t : w2t;
    for (int i = 0; i < 16; i++) {
        int idx = i * 256 + threadIdx.x;
        int k = idx >> 6, n = idx & 63;
        T[n * 64 + k] = f2bf(W[idx]);
    }
}

// ---------------------------------------------------------------------------
// Bucket pass: one sweep over edges; block-local counting sort into 8
// per-XCD streams of packed (src,dst). 8 global atomics per block.
// ---------------------------------------------------------------------------
__global__ __launch_bounds__(256) void bucket_kernel(const int* __restrict__ src,
                                                     const int* __restrict__ dst,
                                                     int* __restrict__ gcnt,   // stride 16
                                                     uint2* __restrict__ buf,
                                                     int nEdges, int nNodes,
                                                     int cap, int ePer) {
    __shared__ int lcnt[NXCD];
    __shared__ int lbase[NXCD];
    __shared__ int lcur[NXCD];
    int tid = threadIdx.x;
    int chunk0 = blockIdx.x * 256 * ePer;

    if (tid < NXCD) lcnt[tid] = 0;
    __syncthreads();

    int es[10], ed[10];   // ePer <= 10
    int cnt = 0;
#pragma unroll
    for (int i = 0; i < 10; i++) {
        if (i >= ePer) break;
        int e = chunk0 + i * 256 + tid;
        if (e < nEdges) {
            es[cnt] = src[e];
            ed[cnt] = dst[e];
            int b = (int)((long long)ed[cnt] * NXCD / nNodes);
            atomicAdd(&lcnt[b], 1);
            cnt++;
        }
    }
    __syncthreads();
    if (tid < NXCD) {
        lbase[tid] = atomicAdd(&gcnt[tid * 16], lcnt[tid]);
        lcur[tid] = 0;
    }
    __syncthreads();
    for (int i = 0; i < cnt; i++) {
        int b = (int)((long long)ed[i] * NXCD / nNodes);
        int p = lbase[b] + atomicAdd(&lcur[b], 1);
        if (p < cap) buf[(size_t)b * cap + p] = make_uint2((unsigned)es[i], (unsigned)ed[i]);
    }
}

// ---------------------------------------------------------------------------
// XCD-local histogram over bucketed edges (sequential reads of own stream).
// ---------------------------------------------------------------------------
__global__ __launch_bounds__(256) void hist_bucket_kernel(const uint2* __restrict__ buf,
                                                          const int* __restrict__ gcnt,
                                                          int* __restrict__ counts,
                                                          int cap, int blocksPerXcd) {
    int xcd = blockIdx.x % NXCD;
    int slice = blockIdx.x / NXCD;
    int n = min(gcnt[xcd * 16], cap);
    const uint2* b = buf + (size_t)xcd * cap;
    int step = blocksPerXcd * 256;
    for (int i = slice * 256 + (int)threadIdx.x; i < n; i += step)
        atomicAdd(&counts[b[i].y], 1);
}

// ---- scan pass A ----
__global__ __launch_bounds__(256) void scan_reduce_kernel(const int* __restrict__ counts,
                                                          int* __restrict__ blockSums,
                                                          int nNodes) {
    __shared__ int ws[4];
    int base = blockIdx.x * SCAN_CHUNK;
    int tid = threadIdx.x;
    int s = 0;
#pragma unroll
    for (int i = 0; i < 4; i++) {
        int idx = base + tid + 256 * i;
        if (idx < nNodes) s += counts[idx];
    }
#pragma unroll
    for (int d = 32; d > 0; d >>= 1) s += __shfl_xor(s, d, 64);
    if ((tid & 63) == 0) ws[tid >> 6] = s;
    __syncthreads();
    if (tid == 0) blockSums[blockIdx.x] = ws[0] + ws[1] + ws[2] + ws[3];
}

// ---- scan pass B ----
__global__ __launch_bounds__(256) void scan_sums_kernel(int* __restrict__ blockSums,
                                                        int* __restrict__ off,
                                                        int nSB, int nNodes, int nEdges) {
    __shared__ int ws[4];
    int tid = threadIdx.x;
    int lane = tid & 63;
    int wave = tid >> 6;
    int v = (tid < nSB) ? blockSums[tid] : 0;
    int incl = v;
#pragma unroll
    for (int d = 1; d < 64; d <<= 1) {
        int t = __shfl_up(incl, d, 64);
        if (lane >= d) incl += t;
    }
    if (lane == 63) ws[wave] = incl;
    __syncthreads();
    int waveOff = 0;
#pragma unroll
    for (int w = 0; w < 4; w++)
        if (w < wave) waveOff += ws[w];
    if (tid < nSB) blockSums[tid] = waveOff + incl - v;
    if (tid == 0) off[nNodes] = nEdges;
}

// ---- scan pass C ----
__global__ __launch_bounds__(1024) void scan_write_kernel(int* __restrict__ off,
                                                          int* __restrict__ cur,
                                                          const int* __restrict__ blockSums,
                                                          int nNodes) {
    __shared__ int waveSums[16];
    int tid = threadIdx.x;
    int lane = tid & 63;
    int wave = tid >> 6;
    int i = blockIdx.x * SCAN_CHUNK + tid;
    int v = (i < nNodes) ? off[i] : 0;
    int incl = v;
#pragma unroll
    for (int d = 1; d < 64; d <<= 1) {
        int t = __shfl_up(incl, d, 64);
        if (lane >= d) incl += t;
    }
    if (lane == 63) waveSums[wave] = incl;
    __syncthreads();
    if (wave == 0) {
        int wv = (lane < 16) ? waveSums[lane] : 0;
        int s = wv;
#pragma unroll
        for (int d = 1; d < 16; d <<= 1) {
            int t = __shfl_up(s, d, 64);
            if (lane >= d) s += t;
        }
        if (lane < 16) waveSums[lane] = s - wv;
    }
    __syncthreads();
    if (i < nNodes) {
        int excl = blockSums[blockIdx.x] + waveSums[wave] + incl - v;
        off[i] = excl;
        cur[i] = excl;
    }
}

// ---------------------------------------------------------------------------
// XCD-local fill from bucketed edges: dirty ssrc lines stay in the XCD's L2.
// ---------------------------------------------------------------------------
__global__ __launch_bounds__(256) void fill_bucket_kernel(const uint2* __restrict__ buf,
                                                          const int* __restrict__ gcnt,
                                                          int* __restrict__ cur,
                                                          int* __restrict__ ssrc,
                                                          int cap, int blocksPerXcd) {
    int xcd = blockIdx.x % NXCD;
    int slice = blockIdx.x / NXCD;
    int n = min(gcnt[xcd * 16], cap);
    const uint2* b = buf + (size_t)xcd * cap;
    int step = blocksPerXcd * 256;
    for (int i = slice * 256 + (int)threadIdx.x; i < n; i += step) {
        uint2 e = b[i];
        int p = atomicAdd(&cur[e.y], 1);
        ssrc[p] = (int)e.x;
    }
}

// --------- fallback sweep kernels (tier 1/2: ws too small for buckets) -----
__global__ __launch_bounds__(256) void hist_xcd_kernel(const int* __restrict__ dst,
                                                       int* __restrict__ counts,
                                                       int nEdges, int nNodes,
                                                       int blocksPerXcd) {
    int xcd = blockIdx.x % NXCD;
    int slice = blockIdx.x / NXCD;
    int lo = (int)((long long)nNodes * xcd / NXCD);
    int hi = (int)((long long)nNodes * (xcd + 1) / NXCD);
    int per = (nEdges + blocksPerXcd - 1) / blocksPerXcd;
    int e0 = slice * per;
    int e1 = min(e0 + per, nEdges);
    for (int e = e0 + (int)threadIdx.x; e < e1; e += 256) {
        int d = dst[e];
        if (d >= lo && d < hi) atomicAdd(&counts[d], 1);
    }
}

__global__ __launch_bounds__(256) void fill_xcd_kernel(const int* __restrict__ src,
                                                       const int* __restrict__ dst,
                                                       int* __restrict__ cur,
                                                       int* __restrict__ ssrc,
                                                       int nEdges, int nNodes,
                                                       int blocksPerXcd) {
    int xcd = blockIdx.x % NXCD;
    int slice = blockIdx.x / NXCD;
    int lo = (int)((long long)nNodes * xcd / NXCD);
    int hi = (int)((long long)nNodes * (xcd + 1) / NXCD);
    int per = (nEdges + blocksPerXcd - 1) / blocksPerXcd;
    int e0 = slice * per;
    int e1 = min(e0 + per, nEdges);
    for (int e = e0 + (int)threadIdx.x; e < e1; e += 256) {
        int d = dst[e];
        if (d >= lo && d < hi) {
            int p = atomicAdd(&cur[d], 1);
            ssrc[p] = src[e];
        }
    }
}

// ---------------------------------------------------------------------------
// Aggregate -> bf16 h: hb[n] = bf16( xh[n] + sum_e xh[ssrc[e]] )
// ---------------------------------------------------------------------------
__global__ __launch_bounds__(256) void aggregate_h_kernel(const ushort_t* __restrict__ xh,
                                                          const int* __restrict__ off,
                                                          const int* __restrict__ ssrc,
                                                          ushort_t* __restrict__ hb,
                                                          int nNodes) {
    int gid = blockIdx.x * 256 + threadIdx.x;
    int n = gid >> 4;
    if (n >= nNodes) return;
    int f = (gid & 15) * 4;
    ushort4 sv = *(const ushort4*)(xh + (size_t)n * D + f);
    float4 acc;
    acc.x = bf2f(sv.x); acc.y = bf2f(sv.y); acc.z = bf2f(sv.z); acc.w = bf2f(sv.w);
    int e0 = off[n], e1 = off[n + 1];
    for (int e = e0; e < e1; e++) {
        int s = ssrc[e];
        ushort4 v = *(const ushort4*)(xh + (size_t)s * D + f);
        acc.x += bf2f(v.x); acc.y += bf2f(v.y); acc.z += bf2f(v.z); acc.w += bf2f(v.w);
    }
    ushort4 o;
    o.x = f2bf(acc.x); o.y = f2bf(acc.y); o.z = f2bf(acc.z); o.w = f2bf(acc.w);
    *(ushort4*)(hb + (size_t)n * D + f) = o;
}

// fp32 fallback aggregate (tier 2)
__global__ __launch_bounds__(256) void aggregate_kernel(const float* __restrict__ x,
                                                        const int* __restrict__ off,
                                                        const int* __restrict__ ssrc,
                                                        float* __restrict__ out,
                                                        int nNodes) {
    int gid = blockIdx.x * 256 + threadIdx.x;
    int n = gid >> 4;
    if (n >= nNodes) return;
    int f = (gid & 15) * 4;
    float4 acc = *(const float4*)(x + (size_t)n * D + f);
    int e0 = off[n], e1 = off[n + 1];
    for (int e = e0; e < e1; e++) {
        int s = ssrc[e];
        float4 v = *(const float4*)(x + (size_t)s * D + f);
        acc.x += v.x; acc.y += v.y; acc.z += v.z; acc.w += v.w;
    }
    *(float4*)(out + (size_t)n * D + f) = acc;
}

// ---------------------------------------------------------------------------
// MFMA MLP: one wave per 16-node tile (see R6 notes for fragment maps).
// ---------------------------------------------------------------------------
#define HSTR 72
__global__ __launch_bounds__(256) void mlp_mfma_kernel(const ushort_t* __restrict__ hb,
                                                       const ushort_t* __restrict__ w1t,
                                                       const ushort_t* __restrict__ w2t,
                                                       const float* __restrict__ b1,
                                                       const float* __restrict__ b2,
                                                       float* __restrict__ out,
                                                       int nNodes, int nTiles) {
    __shared__ ushort_t sh[4][16 * HSTR];
    int lane = threadIdx.x & 63;
    int wave = threadIdx.x >> 6;
    int quad = lane >> 4;
    int col = lane & 15;

    bf16x8 w1f[4][2], w2f[4][2];
#pragma unroll
    for (int nt = 0; nt < 4; nt++)
#pragma unroll
        for (int ks = 0; ks < 2; ks++) {
            int n = nt * 16 + col;
            w1f[nt][ks] = *(const bf16x8*)(w1t + n * 64 + ks * 32 + quad * 8);
            w2f[nt][ks] = *(const bf16x8*)(w2t + n * 64 + ks * 32 + quad * 8);
        }
    float bb1[4], bb2[4];
#pragma unroll
    for (int nt = 0; nt < 4; nt++) {
        bb1[nt] = b1[nt * 16 + col];
        bb2[nt] = b2[nt * 16 + col];
    }

    ushort_t* sw = sh[wave];
    int gw = blockIdx.x * 4 + wave;
    int nW = gridDim.x * 4;
    for (int tile = gw; tile < nTiles; tile += nW) {
        int base = tile * 16;
        int arow = min(base + col, nNodes - 1);
        const ushort_t* hp = hb + (size_t)arow * D;
        bf16x8 a0 = *(const bf16x8*)(hp + quad * 8);
        bf16x8 a1 = *(const bf16x8*)(hp + 32 + quad * 8);

        f32x4 c;
#pragma unroll
        for (int nt = 0; nt < 4; nt++) {
            c = (f32x4){0.f, 0.f, 0.f, 0.f};
            c = __builtin_amdgcn_mfma_f32_16x16x32_bf16(a0, w1f[nt][0], c, 0, 0, 0);
            c = __builtin_amdgcn_mfma_f32_16x16x32_bf16(a1, w1f[nt][1], c, 0, 0, 0);
#pragma unroll
            for (int r = 0; r < 4; r++) {
                float v = fmaxf(c[r] + bb1[nt], 0.0f);
                int m = quad * 4 + r;
                sw[m * HSTR + nt * 16 + col] = f2bf(v);
            }
        }
        bf16x8 d0 = *(const bf16x8*)(sw + col * HSTR + quad * 8);
        bf16x8 d1 = *(const bf16x8*)(sw + col * HSTR + 32 + quad * 8);
#pragma unroll
        for (int nt = 0; nt < 4; nt++) {
            c = (f32x4){0.f, 0.f, 0.f, 0.f};
            c = __builtin_amdgcn_mfma_f32_16x16x32_bf16(d0, w2f[nt][0], c, 0, 0, 0);
            c = __builtin_amdgcn_mfma_f32_16x16x32_bf16(d1, w2f[nt][1], c, 0, 0, 0);
#pragma unroll
            for (int r = 0; r < 4; r++) {
                int row = base + quad * 4 + r;
                if (row < nNodes) out[(size_t)row * D + nt * 16 + col] = c[r] + bb2[nt];
            }
        }
    }
}

// fallback vector-ALU MLP (tier 2)
__global__ __launch_bounds__(256) void mlp_reg_kernel(const float* hin,
                                                      const float* __restrict__ W1,
                                                      const float* __restrict__ b1,
                                                      const float* __restrict__ W2,
                                                      const float* __restrict__ b2,
                                                      float* out,
                                                      int nNodes) {
    int lane = threadIdx.x & 63;
    int wave = threadIdx.x >> 6;
    float w1[D], w2[D];
#pragma unroll
    for (int k = 0; k < D; k++) w1[k] = W1[k * D + lane];
#pragma unroll
    for (int k = 0; k < D; k++) w2[k] = W2[k * D + lane];
    float bb1 = b1[lane];
    float bb2 = b2[lane];
    int gw = blockIdx.x * 4 + wave;
    int nW = gridDim.x * 4;
    for (int n = gw; n < nNodes; n += nW) {
        float hv = hin[(size_t)n * D + lane];
        float a0 = bb1, a1 = 0.0f, a2 = 0.0f, a3 = 0.0f;
#pragma unroll
        for (int k = 0; k < D; k += 4) {
            float h0 = __uint_as_float(__builtin_amdgcn_readlane(__float_as_uint(hv), k + 0));
            float h1 = __uint_as_float(__builtin_amdgcn_readlane(__float_as_uint(hv), k + 1));
            float h2 = __uint_as_float(__builtin_amdgcn_readlane(__float_as_uint(hv), k + 2));
            float h3 = __uint_as_float(__builtin_amdgcn_readlane(__float_as_uint(hv), k + 3));
            a0 = fmaf(h0, w1[k + 0], a0);
            a1 = fmaf(h1, w1[k + 1], a1);
            a2 = fmaf(h2, w1[k + 2], a2);
            a3 = fmaf(h3, w1[k + 3], a3);
        }
        float m = fmaxf((a0 + a1) + (a2 + a3), 0.0f);
        float c0 = bb2, c1 = 0.0f, c2 = 0.0f, c3 = 0.0f;
#pragma unroll
        for (int k = 0; k < D; k += 4) {
            float h0 = __uint_as_float(__builtin_amdgcn_readlane(__float_as_uint(m), k + 0));
            float h1 = __uint_as_float(__builtin_amdgcn_readlane(__float_as_uint(m), k + 1));
            float h2 = __uint_as_float(__builtin_amdgcn_readlane(__float_as_uint(m), k + 2));
            float h3 = __uint_as_float(__builtin_amdgcn_readlane(__float_as_uint(m), k + 3));
            c0 = fmaf(h0, w2[k + 0], c0);
            c1 = fmaf(h1, w2[k + 1], c1);
            c2 = fmaf(h2, w2[k + 2], c2);
            c3 = fmaf(h3, w2[k + 3], c3);
        }
        out[(size_t)n * D + lane] = (c0 + c1) + (c2 + c3);
    }
}

extern "C" void kernel_launch(void* const* d_in, const int* in_sizes, int n_in,
                              void* d_out, int out_size, void* d_ws, size_t ws_size,
                              hipStream_t stream) {
    const float* x  = (const float*)d_in[0];
    const int*   ei = (const int*)d_in[1];
    const float* W1 = (const float*)d_in[2];
    const float* b1 = (const float*)d_in[3];
    const float* W2 = (const float*)d_in[4];
    const float* b2 = (const float*)d_in[5];
    float* out = (float*)d_out;

    const int nNodes = in_sizes[0] / D;
    const int nEdges = in_sizes[1] / 2;
    const int* src = ei;
    const int* dst = ei + nEdges;

    const int nSB = (nNodes + SCAN_CHUNK - 1) / SCAN_CHUNK;
    const int cap = nEdges / NXCD + 65536;

    int* off  = (int*)d_ws;                         // N+1
    int* cur  = off + (nNodes + 1);                 // N
    int* ssrc = cur + nNodes;                       // E
    int* blockSums = ssrc + nEdges;                 // 256
    int* gcnt = blockSums + 256;                    // 128 (8 cursors, stride 16)
    uint2* buf = (uint2*)(gcnt + 128);              // 8*cap
    ushort_t* xh  = (ushort_t*)(buf + (size_t)NXCD * cap);  // N*64
    ushort_t* hb  = xh + (size_t)nNodes * D;        // N*64
    ushort_t* w1t = hb + (size_t)nNodes * D;        // 4096
    ushort_t* w2t = w1t + 4096;                     // 4096

    size_t wsCore  = (size_t)(2 * nNodes + 1 + nEdges + 256 + 128) * 4;
    size_t wsBuf   = (size_t)NXCD * cap * 8;
    size_t wsBf16  = (size_t)nNodes * D * 2 * 2 + 2 * 4096 * 2;
    int tier;
    if (ws_size >= wsCore + wsBuf + wsBf16) tier = 0;        // bucket + bf16 + mfma
    else if (ws_size >= wsCore + wsBf16)    tier = 1;        // sweep + bf16 + mfma
    else                                    tier = 2;        // sweep + fp32 + valu
    if (tier >= 1) {
        // no bucket buffer: re-base bf16 areas right after gcnt
        xh  = (ushort_t*)(gcnt + 128);
        hb  = xh + (size_t)nNodes * D;
        w1t = hb + (size_t)nNodes * D;
        w2t = w1t + 4096;
    }

    // zero counts + bucket cursors
    zero_kernel<<<(nNodes + 1 + 255) / 256, 256, 0, stream>>>(off, nNodes + 1);
    zero_kernel<<<1, 256, 0, stream>>>(gcnt, 128);
    if (tier <= 1) {
        int n4 = nNodes * (D / 4);
        cast_kernel<<<(n4 + 255) / 256, 256, 0, stream>>>((const float4*)x, (ushort4*)xh, n4);
        cast_wT_kernel<<<2, 256, 0, stream>>>(W1, W2, w1t, w2t);
    }

    if (tier == 0) {
        int ePer = (nEdges + BUCKET_BLOCKS * 256 - 1) / (BUCKET_BLOCKS * 256);  // <=10 for E<=1.31M
        if (ePer <= 10) {
            bucket_kernel<<<BUCKET_BLOCKS, 256, 0, stream>>>(src, dst, gcnt, buf,
                                                             nEdges, nNodes, cap, ePer);
            const int bpx = 128;
            hist_bucket_kernel<<<bpx * NXCD, 256, 0, stream>>>(buf, gcnt, off, cap, bpx);
            scan_reduce_kernel<<<nSB, 256, 0, stream>>>(off, blockSums, nNodes);
            scan_sums_kernel<<<1, 256, 0, stream>>>(blockSums, off, nSB, nNodes, nEdges);
            scan_write_kernel<<<nSB, 1024, 0, stream>>>(off, cur, blockSums, nNodes);
            fill_bucket_kernel<<<bpx * NXCD, 256, 0, stream>>>(buf, gcnt, cur, ssrc, cap, bpx);
        } else {
            tier = 1;  // edge count too large for register cache; use sweep
        }
    }
    if (tier >= 1) {
        const int blocksPerXcd = 256;
        hist_xcd_kernel<<<blocksPerXcd * NXCD, 256, 0, stream>>>(
            dst, off, nEdges, nNodes, blocksPerXcd);
        scan_reduce_kernel<<<nSB, 256, 0, stream>>>(off, blockSums, nNodes);
        scan_sums_kernel<<<1, 256, 0, stream>>>(blockSums, off, nSB, nNodes, nEdges);
        scan_write_kernel<<<nSB, 1024, 0, stream>>>(off, cur, blockSums, nNodes);
        fill_xcd_kernel<<<blocksPerXcd * NXCD, 256, 0, stream>>>(
            src, dst, cur, ssrc, nEdges, nNodes, blocksPerXcd);
    }

    long long work = (long long)nNodes * 16;
    int aggBlocks = (int)((work + 255) / 256);
    if (tier <= 1) {
        aggregate_h_kernel<<<aggBlocks, 256, 0, stream>>>(xh, off, ssrc, hb, nNodes);
        int nTiles = (nNodes + 15) / 16;
        int blocks = (nTiles + 3) / 4;
        mlp_mfma_kernel<<<blocks, 256, 0, stream>>>(hb, w1t, w2t, b1, b2, out, nNodes, nTiles);
    } else {
        aggregate_kernel<<<aggBlocks, 256, 0, stream>>>(x, off, ssrc, out, nNodes);
        mlp_reg_kernel<<<6250, 256, 0, stream>>>(out, W1, b1, W2, b2, out, nNodes);
    }
}